// Round 15
// baseline (27.775 us; speedup 1.0000x reference)
//
#include <hip/hip_runtime.h>

// INSTRUMENTATION ROUND 2 (deliberate slow round, data only).
// R14 fact: +1 full gather rep (536 MB L2 reads, 262K instrs) cost 0.006 us
// -> kernel is NOT gather/L2/instruction bound; dur set by HBM write+fetch.
// Unknown: our dispatch's FETCH_SIZE (never in top-5; harness fills ~41 us
// beat our 27.7 us). This kernel: 8x gather reps (store once, per-rep results
// kept alive via asm; memory clobber kills cross-rep CSE) -> ~100+ us of L2
// service -> dispatch surfaces at rank 1 WITH counters.
// Read-out: FETCH ~25 MB -> traffic minimal, 27.7 us is the mixed-stream
// wall -> revert & declare. FETCH 100+ MB -> NT stores pollute L2, weight
// slice refetched -> fetch-reduction lever exists.

#define LVL 8
#define KTOK 1024
#define DIM 512
#define SEQ 4096
#define NB 8
#define CHUNKF 64                  // floats per D-chunk
#define NCHUNK (DIM / CHUNKF)      // 8 chunks, one per XCD
#define REPS 8

typedef float f4 __attribute__((ext_vector_type(4)));

__global__ __launch_bounds__(256) void multi_embed_kernel(
    const int* __restrict__ x, const float* __restrict__ w, float* __restrict__ out) {
  const int tid   = threadIdx.x;
  const int chunk = blockIdx.x & (NCHUNK - 1);  // XCD-pinned D-chunk
  const int rg    = blockIdx.x >> 3;            // row group, 0..2047
  const int slot  = tid & 15;                   // float4 slot within chunk
  const int rloc  = tid >> 4;                   // 16 rows per block
  const int dbase = chunk * CHUNKF + slot * 4;

  const int row = rg * 16 + rloc;               // flat (n*SEQ + s)
  const int n   = row >> 12;
  const int s   = row & (SEQ - 1);

  const int*   xp = x + n * (LVL * SEQ) + s;
  const float* wp = w + dbase;

  f4 acc = {0.f, 0.f, 0.f, 0.f};
  for (int rep = 0; rep < REPS; ++rep) {
    int idx[LVL];
#pragma unroll
    for (int l = 0; l < LVL; ++l) idx[l] = xp[l * SEQ];

    acc = (f4){0.f, 0.f, 0.f, 0.f};
#pragma unroll
    for (int l = 0; l < LVL; ++l)
      acc += *reinterpret_cast<const f4*>(wp + (size_t)(l * KTOK + idx[l]) * DIM);

    // keep this rep's gathers live without an extra store (no DCE, rule #17)
    asm volatile("" :: "v"(acc.x), "v"(acc.y), "v"(acc.z), "v"(acc.w));
    asm volatile("" ::: "memory");  // defeat cross-rep load CSE
  }

  // single store of the (identical) final rep -> output exact, WRITE = 64 MB
  __builtin_nontemporal_store(
      acc, reinterpret_cast<f4*>(out + (size_t)row * DIM + dbase));
}

extern "C" void kernel_launch(void* const* d_in, const int* in_sizes, int n_in,
                              void* d_out, int out_size, void* d_ws, size_t ws_size,
                              hipStream_t stream) {
  const int*   x = (const int*)d_in[0];    // [N, L, S]
  const float* w = (const float*)d_in[1];  // [L, K, D]
  float*     out = (float*)d_out;          // [N, S, D]

  // 32768 rows / 16 per block * 8 chunks = 16384 blocks
  multi_embed_kernel<<<dim3((NB * SEQ / 16) * NCHUNK), dim3(256), 0, stream>>>(x, w, out);
}